// Round 10
// baseline (202.884 us; speedup 1.0000x reference)
//
#include <hip/hip_runtime.h>
#include <hip/hip_bf16.h>
#include <math.h>

// Problem constants (fixed by the reference).
#define DEPTHC 2
#define DIMD   256
#define MLPD   1024
#define BB     2
#define NN     2048
#define HH     8
#define HD     32
#define ROWS   (BB * NN)   // 4096 token rows
#define KSPLIT 4

typedef __attribute__((ext_vector_type(8))) short bf16x8;
typedef __attribute__((ext_vector_type(4))) float f32x4;

__device__ __forceinline__ short f2bf(float x) {
    union { float f; unsigned u; } c; c.f = x;
    unsigned u = c.u + (0x7fffu + ((c.u >> 16) & 1u));
    return (short)(u >> 16);
}
__device__ __forceinline__ float bf2f(short s) {
    union { unsigned u; float f; } c; c.u = ((unsigned)(unsigned short)s) << 16;
    return c.f;
}

// ---------------------------------------------------------------------------
// ONE transpose kernel for all four weights: W[K][N] f32 -> Wt[N][K] bf16.
// ---------------------------------------------------------------------------
__global__ __launch_bounds__(256) void transpose_all(
    const float* __restrict__ Wqkv, const float* __restrict__ Wo,
    const float* __restrict__ W1,   const float* __restrict__ W2,
    short* __restrict__ WqkvT, short* __restrict__ WoT,
    short* __restrict__ W1T,   short* __restrict__ W2T)
{
    __shared__ float t[32][33];
    int blk = blockIdx.x;
    const float* W; short* Wt; int K, N;
    if (blk < 192)      {            W = Wqkv; Wt = WqkvT; K = 256;  N = 768;  }
    else if (blk < 256) { blk -= 192; W = Wo;   Wt = WoT;   K = 256;  N = 256;  }
    else if (blk < 512) { blk -= 256; W = W1;   Wt = W1T;   K = 256;  N = 1024; }
    else                { blk -= 512; W = W2;   Wt = W2T;   K = 1024; N = 256;  }
    const int ntn = N >> 5;
    const int n0 = (blk % ntn) * 32;
    const int k0 = (blk / ntn) * 32;
    const int tx = threadIdx.x & 31;
    const int ty = threadIdx.x >> 5;
#pragma unroll
    for (int i = 0; i < 4; ++i)
        t[ty + 8 * i][tx] = W[(size_t)(k0 + ty + 8 * i) * N + n0 + tx];
    __syncthreads();
#pragma unroll
    for (int i = 0; i < 4; ++i)
        Wt[(size_t)(n0 + ty + 8 * i) * K + k0 + tx] = f2bf(t[tx][ty + 8 * i]);
}

// ---------------------------------------------------------------------------
// V transpose into global: qkv[b][n][512+h*32+d] -> vtg[bh][d][n] (bf16).
// ---------------------------------------------------------------------------
__global__ __launch_bounds__(256) void transpose_v(
    const short* __restrict__ qkv, short* __restrict__ vtg)
{
    __shared__ short Vs[64][33];
    const int tid = threadIdx.x;
    const int bh  = blockIdx.y;
    const int b   = bh >> 3;
    const int h   = bh & 7;
    const int n0  = blockIdx.x * 64;

    const int kk = tid >> 2;
    const int sd = (tid & 3) * 8;
    const bf16x8 tmp = *(const bf16x8*)(
        qkv + ((size_t)(b * NN + n0 + kk)) * (3 * DIMD) + 2 * DIMD + h * HD + sd);
#pragma unroll
    for (int j = 0; j < 8; ++j) Vs[kk][sd + j] = tmp[j];
    __syncthreads();

    const int d  = tid >> 3;
    const int kc = (tid & 7) * 8;
    bf16x8 v;
#pragma unroll
    for (int j = 0; j < 8; ++j) v[j] = Vs[kc + j][d];
    *(bf16x8*)&vtg[((size_t)(bh * HD + d)) * NN + n0 + kc] = v;
}

// ---------------------------------------------------------------------------
// K=256 GEMM core: block tile 64(M) x 128(N), 4 waves, wave = 32x64
// (2x4 accum of 16x16 -> 6 ds_reads per 8 MFMAs). Full-K A resident in LDS
// (staged once); B staged per 64-K chunk with register prefetch.
// ASRC: 0 = LayerNorm from f32 X (Asrc1=g, Asrc2=beta);
//       1 = KSPLIT merge from pO (Asrc0) + pl (Asrc1).
// ---------------------------------------------------------------------------
template <int ASRC, bool GELU, bool RES, bool OBF>
__global__ __launch_bounds__(256) void gemm_k256(
    const void* __restrict__ Asrc0, const float* __restrict__ Asrc1,
    const float* __restrict__ Asrc2, const short* __restrict__ Wt,
    const float* __restrict__ bias, const float* __restrict__ R,
    void* __restrict__ Cv, int N)
{
    __shared__ short As[64][264];   // full K=256, pad +8 (2-way frag reads)
    __shared__ short Bs[128][72];   // one 64-K chunk of B

    const int tid  = threadIdx.x;
    const int w    = tid >> 6;
    const int lane = tid & 63;
    const int quad = lane >> 4;
    const int l16  = lane & 15;
    const int wr   = (w >> 1) * 32;      // wave rows in [0,64)
    const int wc   = (w & 1) * 64;       // wave cols in [0,128)
    const int m0   = blockIdx.y * 64;
    const int n0   = blockIdx.x * 128;

    // ---- A staging ----
    if (ASRC == 0) {
        // LayerNorm: 4 lanes per row (lane = r4*4 + c), 16 rows per wave.
        const int r4 = lane >> 2;
        const int c  = lane & 3;
        const int row = w * 16 + r4;
        const float* xr = (const float*)Asrc0 + (size_t)(m0 + row) * DIMD + c * 64;
        float s = 0.f, sq = 0.f;
#pragma unroll
        for (int i = 0; i < 16; ++i) {
            const float4 v = *(const float4*)&xr[i * 4];
            s  += v.x + v.y + v.z + v.w;
            sq += v.x * v.x + v.y * v.y + v.z * v.z + v.w * v.w;
        }
#pragma unroll
        for (int off = 1; off <= 2; off <<= 1) {
            s  += __shfl_xor(s,  off, 64);
            sq += __shfl_xor(sq, off, 64);
        }
        const float mean = s * (1.f / DIMD);
        const float var  = sq * (1.f / DIMD) - mean * mean;
        const float rstd = rsqrtf(var + 1e-5f);
#pragma unroll
        for (int i = 0; i < 8; ++i) {
            const float4 v0 = *(const float4*)&xr[i * 8];
            const float4 v1 = *(const float4*)&xr[i * 8 + 4];
            const float4 g0 = *(const float4*)&Asrc1[c * 64 + i * 8];
            const float4 g1 = *(const float4*)&Asrc1[c * 64 + i * 8 + 4];
            const float4 b0 = *(const float4*)&Asrc2[c * 64 + i * 8];
            const float4 b1 = *(const float4*)&Asrc2[c * 64 + i * 8 + 4];
            bf16x8 o;
            o[0] = f2bf((v0.x - mean) * rstd * g0.x + b0.x);
            o[1] = f2bf((v0.y - mean) * rstd * g0.y + b0.y);
            o[2] = f2bf((v0.z - mean) * rstd * g0.z + b0.z);
            o[3] = f2bf((v0.w - mean) * rstd * g0.w + b0.w);
            o[4] = f2bf((v1.x - mean) * rstd * g1.x + b1.x);
            o[5] = f2bf((v1.y - mean) * rstd * g1.y + b1.y);
            o[6] = f2bf((v1.z - mean) * rstd * g1.z + b1.z);
            o[7] = f2bf((v1.w - mean) * rstd * g1.w + b1.w);
            *(bf16x8*)&As[row][c * 64 + i * 8] = o;
        }
    } else {
        // KSPLIT merge: (sum_s pO) / (sum_s pl) per (row, head).
        const short* pO = (const short*)Asrc0;
        const int rb = (tid >> 5) * 8;
        const int cc = (tid & 31) * 8;
        const int h  = cc >> 5;
        const int d0 = cc & 31;
#pragma unroll
        for (int i = 0; i < 8; ++i) {
            const int row = m0 + rb + i;
            const int b   = row >> 11;
            const int q   = row & (NN - 1);
            const size_t rg = ((size_t)(b * HH + h) * NN + q) * KSPLIT;
            const float L = Asrc1[rg] + Asrc1[rg + 1] + Asrc1[rg + 2] + Asrc1[rg + 3];
            float o[8] = {};
#pragma unroll
            for (int s = 0; s < KSPLIT; ++s) {
                const bf16x8 t = *(const bf16x8*)&pO[(rg + s) * HD + d0];
#pragma unroll
                for (int j = 0; j < 8; ++j) o[j] += bf2f(t[j]);
            }
            const float inv = 1.f / L;
#pragma unroll
            for (int j = 0; j < 8; ++j) As[rb + i][cc + j] = f2bf(o[j] * inv);
        }
    }

    // ---- B staging indices: thread covers row brow, 32-short half bc ----
    const int brow = tid >> 1;            // 0..127
    const int bc   = (tid & 1) * 32;      // 0 or 32 shorts
    const short* bgp = Wt + (size_t)(n0 + brow) * DIMD + bc;

    bf16x8 breg[4];
#pragma unroll
    for (int i = 0; i < 4; ++i) breg[i] = *(const bf16x8*)(bgp + i * 8);

    f32x4 acc[2][4] = {};

#pragma unroll 1
    for (int ch = 0; ch < 4; ++ch) {
        __syncthreads();                   // prior chunk's Bs reads (and As writes) done
#pragma unroll
        for (int i = 0; i < 4; ++i) *(bf16x8*)&Bs[brow][bc + i * 8] = breg[i];
        __syncthreads();
        if (ch + 1 < 4) {
#pragma unroll
            for (int i = 0; i < 4; ++i)
                breg[i] = *(const bf16x8*)(bgp + (ch + 1) * 64 + i * 8);
        }
#pragma unroll
        for (int kc = 0; kc < 2; ++kc) {
            bf16x8 af[2], bfr[4];
#pragma unroll
            for (int i = 0; i < 2; ++i)
                af[i] = *(const bf16x8*)&As[wr + i * 16 + l16][ch * 64 + kc * 32 + quad * 8];
#pragma unroll
            for (int j = 0; j < 4; ++j)
                bfr[j] = *(const bf16x8*)&Bs[wc + j * 16 + l16][kc * 32 + quad * 8];
#pragma unroll
            for (int i = 0; i < 2; ++i)
#pragma unroll
                for (int j = 0; j < 4; ++j)
                    acc[i][j] = __builtin_amdgcn_mfma_f32_16x16x32_bf16(
                        af[i], bfr[j], acc[i][j], 0, 0, 0);
        }
    }

    // ---- epilogue ----
#pragma unroll
    for (int i = 0; i < 2; ++i)
#pragma unroll
    for (int j = 0; j < 4; ++j)
#pragma unroll
    for (int r = 0; r < 4; ++r) {
        const int row = m0 + wr + i * 16 + quad * 4 + r;
        const int col = n0 + wc + j * 16 + l16;
        float v = acc[i][j][r] + bias[col];
        if (RES)  v += R[(size_t)row * N + col];
        if (GELU) v = 0.5f * v * (1.f + erff(v * 0.70710678118f));
        if (OBF) ((short*)Cv)[(size_t)row * N + col] = f2bf(v);
        else     ((float*)Cv)[(size_t)row * N + col] = v;
    }
}

// ---------------------------------------------------------------------------
// W2 GEMM (K=1024): block 64x128, chunked A+B (BK=64), register prefetch
// for both. C = A @ W2T^T + b2 + a (f32 out). Grid: (2, 64).
// ---------------------------------------------------------------------------
__global__ __launch_bounds__(256) void w2_gemm(
    const short* __restrict__ A, const short* __restrict__ Wt,
    const float* __restrict__ bias, const float* __restrict__ R,
    float* __restrict__ C)
{
    __shared__ short As[64][72];
    __shared__ short Bs[128][72];

    const int tid  = threadIdx.x;
    const int w    = tid >> 6;
    const int lane = tid & 63;
    const int quad = lane >> 4;
    const int l16  = lane & 15;
    const int wr   = (w >> 1) * 32;
    const int wc   = (w & 1) * 64;
    const int m0   = blockIdx.y * 64;
    const int n0   = blockIdx.x * 128;

    const int arow = tid >> 2;             // 0..63
    const int ac   = (tid & 3) * 16;       // shorts: 0,16,32,48
    const int brow = tid >> 1;             // 0..127
    const int bc   = (tid & 1) * 32;

    const short* agp = A  + (size_t)(m0 + arow) * MLPD + ac;
    const short* bgp = Wt + (size_t)(n0 + brow) * MLPD + bc;

    bf16x8 areg[2], breg[4];
#pragma unroll
    for (int i = 0; i < 2; ++i) areg[i] = *(const bf16x8*)(agp + i * 8);
#pragma unroll
    for (int i = 0; i < 4; ++i) breg[i] = *(const bf16x8*)(bgp + i * 8);

    f32x4 acc[2][4] = {};

#pragma unroll 1
    for (int ch = 0; ch < MLPD / 64; ++ch) {
        __syncthreads();
#pragma unroll
        for (int i = 0; i < 2; ++i) *(bf16x8*)&As[arow][ac + i * 8] = areg[i];
#pragma unroll
        for (int i = 0; i < 4; ++i) *(bf16x8*)&Bs[brow][bc + i * 8] = breg[i];
        __syncthreads();
        if (ch + 1 < MLPD / 64) {
#pragma unroll
            for (int i = 0; i < 2; ++i)
                areg[i] = *(const bf16x8*)(agp + (ch + 1) * 64 + i * 8);
#pragma unroll
            for (int i = 0; i < 4; ++i)
                breg[i] = *(const bf16x8*)(bgp + (ch + 1) * 64 + i * 8);
        }
#pragma unroll
        for (int kc = 0; kc < 2; ++kc) {
            bf16x8 af[2], bfr[4];
#pragma unroll
            for (int i = 0; i < 2; ++i)
                af[i] = *(const bf16x8*)&As[wr + i * 16 + l16][kc * 32 + quad * 8];
#pragma unroll
            for (int j = 0; j < 4; ++j)
                bfr[j] = *(const bf16x8*)&Bs[wc + j * 16 + l16][kc * 32 + quad * 8];
#pragma unroll
            for (int i = 0; i < 2; ++i)
#pragma unroll
                for (int j = 0; j < 4; ++j)
                    acc[i][j] = __builtin_amdgcn_mfma_f32_16x16x32_bf16(
                        af[i], bfr[j], acc[i][j], 0, 0, 0);
        }
    }

#pragma unroll
    for (int i = 0; i < 2; ++i)
#pragma unroll
    for (int j = 0; j < 4; ++j)
#pragma unroll
    for (int r = 0; r < 4; ++r) {
        const int row = m0 + wr + i * 16 + quad * 4 + r;
        const int col = n0 + wc + j * 16 + l16;
        C[(size_t)row * DIMD + col] = acc[i][j][r] + bias[col] + R[(size_t)row * DIMD + col];
    }
}

// ---------------------------------------------------------------------------
// MFMA flash attention (round-8 version, unchanged).
// ---------------------------------------------------------------------------
__global__ __launch_bounds__(256) void attn_mfma(
    const short* __restrict__ qkv, const short* __restrict__ vtg,
    short* __restrict__ pO, float* __restrict__ pl)
{
    __shared__ short Ks[64][40];
    __shared__ short Vs[32][72];
    __shared__ short Ps[4][16][72];

    const int tid  = threadIdx.x;
    const int w    = tid >> 6;
    const int lane = tid & 63;
    const int quad = lane >> 4;
    const int l16  = lane & 15;
    const int bh   = blockIdx.y;
    const int b    = bh >> 3;
    const int h    = bh & 7;
    const int ks   = blockIdx.z;
    const int q0   = blockIdx.x * 64 + w * 16;

    const float scale = 0.17677669529663689f;    // 32^-0.5
    const float shift = 11.090354888959125f;     // 16*ln2
    const short* base = qkv + (size_t)b * NN * (3 * DIMD);

    const bf16x8 qfrag =
        *(const bf16x8*)(base + (size_t)(q0 + l16) * (3 * DIMD) + h * HD + quad * 8);

    const int skey = tid >> 2;
    const int sd   = (tid & 3) * 8;
    const int vd   = tid >> 3;
    const int vk   = (tid & 7) * 8;

    const short* kgp = base + (size_t)(ks * (NN / KSPLIT) + skey) * (3 * DIMD)
                       + DIMD + h * HD + sd;
    const short* vgp = vtg + ((size_t)bh * HD + vd) * NN
                       + ks * (NN / KSPLIT) + vk;

    f32x4 oacc0 = {0.f, 0.f, 0.f, 0.f};
    f32x4 oacc1 = {0.f, 0.f, 0.f, 0.f};
    float rowsum[4] = {0.f, 0.f, 0.f, 0.f};

    bf16x8 kreg = *(const bf16x8*)kgp;
    bf16x8 vreg = *(const bf16x8*)vgp;

#pragma unroll 1
    for (int t = 0; t < NN / KSPLIT / 64; ++t) {
        __syncthreads();
        *(bf16x8*)&Ks[skey][sd] = kreg;
        *(bf16x8*)&Vs[vd][vk]   = vreg;
        __syncthreads();

        if (t + 1 < NN / KSPLIT / 64) {
            kreg = *(const bf16x8*)(kgp + (size_t)(t + 1) * 64 * (3 * DIMD));
            vreg = *(const bf16x8*)(vgp + (t + 1) * 64);
        }

        f32x4 s[4];
#pragma unroll
        for (int kt = 0; kt < 4; ++kt) {
            const bf16x8 kf = *(const bf16x8*)&Ks[kt * 16 + l16][quad * 8];
            f32x4 z = {0.f, 0.f, 0.f, 0.f};
            s[kt] = __builtin_amdgcn_mfma_f32_16x16x32_bf16(qfrag, kf, z, 0, 0, 0);
        }

#pragma unroll
        for (int kt = 0; kt < 4; ++kt)
#pragma unroll
            for (int r = 0; r < 4; ++r) {
                const float p = __expf(fmaf(s[kt][r], scale, -shift));
                rowsum[r] += p;
                union { float f; unsigned u; } cv; cv.f = p;
                Ps[w][quad * 4 + r][kt * 16 + l16] = (short)(cv.u >> 16);
            }

#pragma unroll
        for (int c = 0; c < 2; ++c) {
            const bf16x8 pf = *(const bf16x8*)&Ps[w][l16][c * 32 + quad * 8];
            const bf16x8 v0 = *(const bf16x8*)&Vs[l16][c * 32 + quad * 8];
            const bf16x8 v1 = *(const bf16x8*)&Vs[16 + l16][c * 32 + quad * 8];
            oacc0 = __builtin_amdgcn_mfma_f32_16x16x32_bf16(pf, v0, oacc0, 0, 0, 0);
            oacc1 = __builtin_amdgcn_mfma_f32_16x16x32_bf16(pf, v1, oacc1, 0, 0, 0);
        }
    }

#pragma unroll
    for (int off = 1; off <= 8; off <<= 1)
#pragma unroll
        for (int r = 0; r < 4; ++r)
            rowsum[r] += __shfl_xor(rowsum[r], off, 64);

#pragma unroll
    for (int r = 0; r < 4; ++r) {
        const size_t rg = (size_t)bh * NN + q0 + quad * 4 + r;
        pO[(rg * KSPLIT + ks) * HD + l16]      = f2bf(oacc0[r]);
        pO[(rg * KSPLIT + ks) * HD + 16 + l16] = f2bf(oacc1[r]);
        if (l16 == 0) pl[rg * KSPLIT + ks] = rowsum[r];
    }
}

// ---------------------------------------------------------------------------
// Launch: only the LAST layer matters (reference never feeds `out` back).
// 7 kernels.
// ---------------------------------------------------------------------------
extern "C" void kernel_launch(void* const* d_in, const int* in_sizes, int n_in,
                              void* d_out, int out_size, void* d_ws, size_t ws_size,
                              hipStream_t stream)
{
    const int L = DEPTHC - 1;
    const float* x     = (const float*)d_in[0];
    const float* ln1_g = (const float*)d_in[1]  + L * DIMD;
    const float* ln1_b = (const float*)d_in[2]  + L * DIMD;
    const float* Wqkv  = (const float*)d_in[3]  + (size_t)L * DIMD * 3 * DIMD;
    const float* bqkv  = (const float*)d_in[4]  + L * 3 * DIMD;
    const float* Wo    = (const float*)d_in[5]  + (size_t)L * DIMD * DIMD;
    const float* bo    = (const float*)d_in[6]  + L * DIMD;
    const float* ln2_g = (const float*)d_in[7]  + L * DIMD;
    const float* ln2_b = (const float*)d_in[8]  + L * DIMD;
    const float* W1    = (const float*)d_in[9]  + (size_t)L * DIMD * MLPD;
    const float* b1    = (const float*)d_in[10] + L * MLPD;
    const float* W2    = (const float*)d_in[11] + (size_t)L * MLPD * DIMD;
    const float* b2    = (const float*)d_in[12] + L * DIMD;
    float* out = (float*)d_out;

    short* WqkvT = (short*)d_ws;                          // [768][256]
    short* WoT   = WqkvT + 768 * 256;                     // [256][256]
    short* W1T   = WoT   + 256 * 256;                     // [1024][256]
    short* W2T   = W1T   + 1024 * 256;                    // [256][1024]
    short* qkvbf = W2T   + 256 * 1024;                    // [4096][768]
    short* vtg   = qkvbf + (size_t)ROWS * 3 * DIMD;       // [16][32][2048]
    short* pO    = vtg   + (size_t)16 * HD * NN;          // [32768][4][32]
    short* m1bf  = pO    + (size_t)16 * NN * KSPLIT * HD; // [4096][1024]
    float* pl    = (float*)(m1bf + (size_t)ROWS * MLPD);  // [32768][4]
    float* a     = pl + (size_t)16 * NN * KSPLIT;         // [4096][256] f32

    // 0) all weight transposes
    transpose_all<<<768, 256, 0, stream>>>(Wqkv, Wo, W1, W2, WqkvT, WoT, W1T, W2T);

    // 1) qkv = LN1(x) @ Wqkv + bqkv        (LN fused; bf16 out)
    gemm_k256<0, false, false, true><<<dim3(3 * DIMD / 128, ROWS / 64), 256, 0, stream>>>(
        x, ln1_g, ln1_b, WqkvT, bqkv, nullptr, qkvbf, 3 * DIMD);

    // 2) V transpose
    transpose_v<<<dim3(NN / 64, BB * HH), 256, 0, stream>>>(qkvbf, vtg);

    // 3) attention partials (4-way key split)
    attn_mfma<<<dim3(NN / 64, BB * HH, KSPLIT), 256, 0, stream>>>(qkvbf, vtg, pO, pl);

    // 4) a = merge(pO,pl) @ Wo + bo + x    (merge fused; f32 out)
    gemm_k256<1, false, true, false><<<dim3(DIMD / 128, ROWS / 64), 256, 0, stream>>>(
        pO, pl, nullptr, WoT, bo, x, a, DIMD);

    // 5) m1 = gelu(LN2(a) @ W1 + b1)       (LN fused; bf16 out)
    gemm_k256<0, true, false, true><<<dim3(MLPD / 128, ROWS / 64), 256, 0, stream>>>(
        a, ln2_g, ln2_b, W1T, b1, nullptr, m1bf, MLPD);

    // 6) out = m1 @ W2 + b2 + a            (f32 out)
    w2_gemm<<<dim3(DIMD / 128, ROWS / 64), 256, 0, stream>>>(m1bf, W2T, b2, a, out);
}

// Round 11
// 168.432 us; speedup vs baseline: 1.2045x; 1.2045x over previous
//
#include <hip/hip_runtime.h>
#include <hip/hip_bf16.h>
#include <math.h>

// Problem constants (fixed by the reference).
#define DEPTHC 2
#define DIMD   256
#define MLPD   1024
#define BB     2
#define NN     2048
#define HH     8
#define HD     32
#define ROWS   (BB * NN)   // 4096 token rows
#define KSPLIT 4

typedef __attribute__((ext_vector_type(8))) short bf16x8;
typedef __attribute__((ext_vector_type(4))) float f32x4;

__device__ __forceinline__ short f2bf(float x) {
    union { float f; unsigned u; } c; c.f = x;
    unsigned u = c.u + (0x7fffu + ((c.u >> 16) & 1u));
    return (short)(u >> 16);
}
__device__ __forceinline__ float bf2f(short s) {
    union { unsigned u; float f; } c; c.u = ((unsigned)(unsigned short)s) << 16;
    return c.f;
}

// ---------------------------------------------------------------------------
// Weight transpose + f32->bf16 into MFMA-FRAGMENT-ORDERED layout.
// For each (64-col N-strip, 128-K chunk): 1024 units of 8 bf16, unit index
// u = ((kstep*4 + nt)*4 + quad)*16 + l16 holds B[n = nt*16+l16]
// [k = (kstep*4+quad)*8 .. +8].  GEMM B-staging then is a pure linear copy.
// Grid: 96 blocks (qkv 24, wo 8, w1 32, w2 32).
// ---------------------------------------------------------------------------
__global__ __launch_bounds__(256) void transpose_frag(
    const float* __restrict__ Wqkv, const float* __restrict__ Wo,
    const float* __restrict__ W1,   const float* __restrict__ W2,
    short* __restrict__ WqkvF, short* __restrict__ WoF,
    short* __restrict__ W1F,   short* __restrict__ W2F)
{
    __shared__ short Ts[128][72];    // [k][n] bf16 tile
    int blk = blockIdx.x;
    const float* W; short* WF; int K, N;
    if (blk < 24)      {           W = Wqkv; WF = WqkvF; K = 256;  N = 768;  }
    else if (blk < 32) { blk -= 24; W = Wo;   WF = WoF;   K = 256;  N = 256;  }
    else if (blk < 64) { blk -= 32; W = W1;   WF = W1F;   K = 256;  N = 1024; }
    else               { blk -= 64; W = W2;   WF = W2F;   K = 1024; N = 256;  }
    const int nkc = K >> 7;            // K/128
    const int bx  = blk / nkc;         // N-strip
    const int kc  = blk % nkc;
    const int n0  = bx * 64;
    const int k0  = kc * 128;

    // coalesced read of the 128k x 64n tile
    const int nc  = threadIdx.x & 63;
    const int kr0 = threadIdx.x >> 6;  // 0..3
#pragma unroll
    for (int i = 0; i < 32; ++i) {
        const int kr = kr0 + i * 4;
        Ts[kr][nc] = f2bf(W[(size_t)(k0 + kr) * N + n0 + nc]);
    }
    __syncthreads();

    short* out = WF + ((size_t)bx * nkc + kc) * 8192;
#pragma unroll
    for (int i = 0; i < 4; ++i) {
        const int u    = threadIdx.x + i * 256;
        const int l16  = u & 15;
        const int quad = (u >> 4) & 3;
        const int nt   = (u >> 6) & 3;
        const int ks   = (u >> 8) & 3;
        const int n    = nt * 16 + l16;
        const int kk   = (ks * 4 + quad) * 8;
        bf16x8 v;
#pragma unroll
        for (int j = 0; j < 8; ++j) v[j] = Ts[kk + j][n];
        *(bf16x8*)&out[(size_t)u * 8] = v;
    }
}

// ---------------------------------------------------------------------------
// Barrier-free single-wave GEMM for short K.
// Block = 1 wave; wave tile 64(M) x 64(N) = 4x4 16-tiles; K in 128-chunks.
// B chunk (16 KB, frag-ordered) linear-copied into LDS (conflict-free);
// A-frags gathered directly from global (16 B/lane; 64-row set = 32 KB = L1).
// Software-pipelined A prefetch. ~10 blocks/CU (16 KB LDS).
// C[M,N] = epi(A[M,K] @ B[N,K]^T + bias (+R) (gelu?)).
// ---------------------------------------------------------------------------
template <int K, bool GELU, bool RES, bool OBF>
__global__ __launch_bounds__(64) void gemm_1w(
    const short* __restrict__ A,    // [M][K] bf16
    const short* __restrict__ WF,   // frag-ordered weights
    const float* __restrict__ bias, const float* __restrict__ R,
    void* __restrict__ Cv, int N)
{
    __shared__ short Bs[8192];      // one 64n x 128k chunk

    const int lane = threadIdx.x;
    const int quad = lane >> 4;
    const int l16  = lane & 15;
    const int n0   = blockIdx.x * 64;
    const int m0   = blockIdx.y * 64;
    constexpr int NKC = K / 128;

    const short* wfb  = WF + (size_t)blockIdx.x * NKC * 8192;
    const short* arow = A + (size_t)(m0 + l16) * K + quad * 8;

    f32x4 acc[4][4] = {};

    bf16x8 af[4], afn[4];
#pragma unroll
    for (int mt = 0; mt < 4; ++mt)
        af[mt] = *(const bf16x8*)(arow + (size_t)mt * 16 * K);

#pragma unroll 1
    for (int kc = 0; kc < NKC; ++kc) {
        // stage B chunk: 1024 units / 64 lanes = 16 linear copies
        const short* src = wfb + (size_t)kc * 8192;
#pragma unroll
        for (int r = 0; r < 16; ++r) {
            const int u = r * 64 + lane;
            *(bf16x8*)&Bs[u * 8] = *(const bf16x8*)&src[(size_t)u * 8];
        }

#pragma unroll
        for (int ks = 0; ks < 4; ++ks) {
            // prefetch A-frags for next kstep
            const int knext = kc * 128 + (ks + 1) * 32;
            if (knext < K) {
#pragma unroll
                for (int mt = 0; mt < 4; ++mt)
                    afn[mt] = *(const bf16x8*)(arow + (size_t)mt * 16 * K + knext);
            }
#pragma unroll
            for (int nt = 0; nt < 4; ++nt) {
                const bf16x8 bf = *(const bf16x8*)
                    &Bs[((((ks * 4 + nt) * 4 + quad) * 16) + l16) * 8];
#pragma unroll
                for (int mt = 0; mt < 4; ++mt)
                    acc[mt][nt] = __builtin_amdgcn_mfma_f32_16x16x32_bf16(
                        af[mt], bf, acc[mt][nt], 0, 0, 0);
            }
#pragma unroll
            for (int mt = 0; mt < 4; ++mt) af[mt] = afn[mt];
        }
    }

#pragma unroll
    for (int mt = 0; mt < 4; ++mt)
#pragma unroll
    for (int nt = 0; nt < 4; ++nt)
#pragma unroll
    for (int r = 0; r < 4; ++r) {
        const int row = m0 + mt * 16 + quad * 4 + r;
        const int col = n0 + nt * 16 + l16;
        float v = acc[mt][nt][r] + bias[col];
        if (RES)  v += R[(size_t)row * N + col];
        if (GELU) v = 0.5f * v * (1.f + erff(v * 0.70710678118f));
        if (OBF) ((short*)Cv)[(size_t)row * N + col] = f2bf(v);
        else     ((float*)Cv)[(size_t)row * N + col] = v;
    }
}

// ---------------------------------------------------------------------------
// LayerNorm: one wave per 256-elem row, 4 rows/block. f32 in, bf16 out.
// ---------------------------------------------------------------------------
__global__ __launch_bounds__(256) void ln_kernel(
    const float* __restrict__ x, const float* __restrict__ g,
    const float* __restrict__ bta, short* __restrict__ y)
{
    const int wave = threadIdx.x >> 6;
    const int lane = threadIdx.x & 63;
    const int row  = blockIdx.x * 4 + wave;
    const int c    = lane * 4;

    const float4 v = *(const float4*)&x[(size_t)row * DIMD + c];
    float s  = v.x + v.y + v.z + v.w;
    float sq = v.x * v.x + v.y * v.y + v.z * v.z + v.w * v.w;
#pragma unroll
    for (int off = 32; off > 0; off >>= 1) {
        s  += __shfl_down(s,  off, 64);
        sq += __shfl_down(sq, off, 64);
    }
    s  = __shfl(s,  0, 64);
    sq = __shfl(sq, 0, 64);

    const float mean = s * (1.f / DIMD);
    const float var  = sq * (1.f / DIMD) - mean * mean;
    const float rstd = rsqrtf(var + 1e-5f);

    const float4 gg = *(const float4*)&g[c];
    const float4 bb = *(const float4*)&bta[c];
    short4 ov;
    ov.x = f2bf((v.x - mean) * rstd * gg.x + bb.x);
    ov.y = f2bf((v.y - mean) * rstd * gg.y + bb.y);
    ov.z = f2bf((v.z - mean) * rstd * gg.z + bb.z);
    ov.w = f2bf((v.w - mean) * rstd * gg.w + bb.w);
    *(short4*)&y[(size_t)row * DIMD + c] = ov;
}

// ---------------------------------------------------------------------------
// V transpose into global: qkv[b][n][512+h*32+d] -> vtg[bh][d][n] (bf16).
// ---------------------------------------------------------------------------
__global__ __launch_bounds__(256) void transpose_v(
    const short* __restrict__ qkv, short* __restrict__ vtg)
{
    __shared__ short Vs[64][33];
    const int tid = threadIdx.x;
    const int bh  = blockIdx.y;
    const int b   = bh >> 3;
    const int h   = bh & 7;
    const int n0  = blockIdx.x * 64;

    const int kk = tid >> 2;
    const int sd = (tid & 3) * 8;
    const bf16x8 tmp = *(const bf16x8*)(
        qkv + ((size_t)(b * NN + n0 + kk)) * (3 * DIMD) + 2 * DIMD + h * HD + sd);
#pragma unroll
    for (int j = 0; j < 8; ++j) Vs[kk][sd + j] = tmp[j];
    __syncthreads();

    const int d  = tid >> 3;
    const int kc = (tid & 7) * 8;
    bf16x8 v;
#pragma unroll
    for (int j = 0; j < 8; ++j) v[j] = Vs[kc + j][d];
    *(bf16x8*)&vtg[((size_t)(bh * HD + d)) * NN + n0 + kc] = v;
}

// ---------------------------------------------------------------------------
// MFMA flash attention (round-8 proven): LDS-staged K/V + fixed-shift softmax
// + 1-tile register prefetch. 4-way key-split. Unnormalized partials out.
// ---------------------------------------------------------------------------
__global__ __launch_bounds__(256) void attn_mfma(
    const short* __restrict__ qkv, const short* __restrict__ vtg,
    short* __restrict__ pO, float* __restrict__ pl)
{
    __shared__ short Ks[64][40];
    __shared__ short Vs[32][72];
    __shared__ short Ps[4][16][72];

    const int tid  = threadIdx.x;
    const int w    = tid >> 6;
    const int lane = tid & 63;
    const int quad = lane >> 4;
    const int l16  = lane & 15;
    const int bh   = blockIdx.y;
    const int b    = bh >> 3;
    const int h    = bh & 7;
    const int ks   = blockIdx.z;
    const int q0   = blockIdx.x * 64 + w * 16;

    const float scale = 0.17677669529663689f;    // 32^-0.5
    const float shift = 11.090354888959125f;     // 16*ln2
    const short* base = qkv + (size_t)b * NN * (3 * DIMD);

    const bf16x8 qfrag =
        *(const bf16x8*)(base + (size_t)(q0 + l16) * (3 * DIMD) + h * HD + quad * 8);

    const int skey = tid >> 2;
    const int sd   = (tid & 3) * 8;
    const int vd   = tid >> 3;
    const int vk   = (tid & 7) * 8;

    const short* kgp = base + (size_t)(ks * (NN / KSPLIT) + skey) * (3 * DIMD)
                       + DIMD + h * HD + sd;
    const short* vgp = vtg + ((size_t)bh * HD + vd) * NN
                       + ks * (NN / KSPLIT) + vk;

    f32x4 oacc0 = {0.f, 0.f, 0.f, 0.f};
    f32x4 oacc1 = {0.f, 0.f, 0.f, 0.f};
    float rowsum[4] = {0.f, 0.f, 0.f, 0.f};

    bf16x8 kreg = *(const bf16x8*)kgp;
    bf16x8 vreg = *(const bf16x8*)vgp;

#pragma unroll 1
    for (int t = 0; t < NN / KSPLIT / 64; ++t) {
        __syncthreads();
        *(bf16x8*)&Ks[skey][sd] = kreg;
        *(bf16x8*)&Vs[vd][vk]   = vreg;
        __syncthreads();

        if (t + 1 < NN / KSPLIT / 64) {
            kreg = *(const bf16x8*)(kgp + (size_t)(t + 1) * 64 * (3 * DIMD));
            vreg = *(const bf16x8*)(vgp + (t + 1) * 64);
        }

        f32x4 s[4];
#pragma unroll
        for (int kt = 0; kt < 4; ++kt) {
            const bf16x8 kf = *(const bf16x8*)&Ks[kt * 16 + l16][quad * 8];
            f32x4 z = {0.f, 0.f, 0.f, 0.f};
            s[kt] = __builtin_amdgcn_mfma_f32_16x16x32_bf16(qfrag, kf, z, 0, 0, 0);
        }

#pragma unroll
        for (int kt = 0; kt < 4; ++kt)
#pragma unroll
            for (int r = 0; r < 4; ++r) {
                const float p = __expf(fmaf(s[kt][r], scale, -shift));
                rowsum[r] += p;
                union { float f; unsigned u; } cv; cv.f = p;
                Ps[w][quad * 4 + r][kt * 16 + l16] = (short)(cv.u >> 16);
            }

#pragma unroll
        for (int c = 0; c < 2; ++c) {
            const bf16x8 pf = *(const bf16x8*)&Ps[w][l16][c * 32 + quad * 8];
            const bf16x8 v0 = *(const bf16x8*)&Vs[l16][c * 32 + quad * 8];
            const bf16x8 v1 = *(const bf16x8*)&Vs[16 + l16][c * 32 + quad * 8];
            oacc0 = __builtin_amdgcn_mfma_f32_16x16x32_bf16(pf, v0, oacc0, 0, 0, 0);
            oacc1 = __builtin_amdgcn_mfma_f32_16x16x32_bf16(pf, v1, oacc1, 0, 0, 0);
        }
    }

#pragma unroll
    for (int off = 1; off <= 8; off <<= 1)
#pragma unroll
        for (int r = 0; r < 4; ++r)
            rowsum[r] += __shfl_xor(rowsum[r], off, 64);

#pragma unroll
    for (int r = 0; r < 4; ++r) {
        const size_t rg = (size_t)bh * NN + q0 + quad * 4 + r;
        pO[(rg * KSPLIT + ks) * HD + l16]      = f2bf(oacc0[r]);
        pO[(rg * KSPLIT + ks) * HD + 16 + l16] = f2bf(oacc1[r]);
        if (l16 == 0) pl[rg * KSPLIT + ks] = rowsum[r];
    }
}

// ---------------------------------------------------------------------------
// Merge KSPLIT partials (shared fixed shift -> plain sum), bf16 out.
// ---------------------------------------------------------------------------
__global__ __launch_bounds__(256) void attn_merge(
    const short* __restrict__ pO, const float* __restrict__ pl,
    short* __restrict__ o)
{
    const int idx = blockIdx.x * 256 + threadIdx.x;
    const int r   = idx >> 5;          // global (bh, q) row
    const int d   = idx & 31;

    float L = 0.f, O = 0.f;
#pragma unroll
    for (int s = 0; s < KSPLIT; ++s) {
        L += pl[r * KSPLIT + s];
        O += bf2f(pO[(size_t)(r * KSPLIT + s) * HD + d]);
    }
    const int bh = r >> 11;
    const int q  = r & (NN - 1);
    const int b  = bh >> 3;
    const int h  = bh & 7;
    o[((size_t)(b * NN + q)) * DIMD + h * HD + d] = f2bf(O / L);
}

// ---------------------------------------------------------------------------
// Launch: only the LAST layer matters (reference never feeds `out` back).
// ---------------------------------------------------------------------------
extern "C" void kernel_launch(void* const* d_in, const int* in_sizes, int n_in,
                              void* d_out, int out_size, void* d_ws, size_t ws_size,
                              hipStream_t stream)
{
    const int L = DEPTHC - 1;
    const float* x     = (const float*)d_in[0];
    const float* ln1_g = (const float*)d_in[1]  + L * DIMD;
    const float* ln1_b = (const float*)d_in[2]  + L * DIMD;
    const float* Wqkv  = (const float*)d_in[3]  + (size_t)L * DIMD * 3 * DIMD;
    const float* bqkv  = (const float*)d_in[4]  + L * 3 * DIMD;
    const float* Wo    = (const float*)d_in[5]  + (size_t)L * DIMD * DIMD;
    const float* bo    = (const float*)d_in[6]  + L * DIMD;
    const float* ln2_g = (const float*)d_in[7]  + L * DIMD;
    const float* ln2_b = (const float*)d_in[8]  + L * DIMD;
    const float* W1    = (const float*)d_in[9]  + (size_t)L * DIMD * MLPD;
    const float* b1    = (const float*)d_in[10] + L * MLPD;
    const float* W2    = (const float*)d_in[11] + (size_t)L * MLPD * DIMD;
    const float* b2    = (const float*)d_in[12] + L * DIMD;
    float* out = (float*)d_out;

    // Workspace layout (shorts unless noted):
    short* WqkvF = (short*)d_ws;                          // 12*2*8192
    short* WoF   = WqkvF + 12 * 2 * 8192;                 // 4*2*8192
    short* W1F   = WoF   + 4 * 2 * 8192;                  // 16*2*8192
    short* W2F   = W1F   + 16 * 2 * 8192;                 // 4*8*8192
    short* ybf   = W2F   + 4 * 8 * 8192;                  // [4096][256]
    short* zbf   = ybf   + (size_t)ROWS * DIMD;           // [4096][256]
    short* qkvbf = zbf   + (size_t)ROWS * DIMD;           // [4096][768]
    short* vtg   = qkvbf + (size_t)ROWS * 3 * DIMD;       // [16][32][2048]
    short* obf   = vtg   + (size_t)16 * HD * NN;          // [4096][256]
    short* pO    = obf   + (size_t)ROWS * DIMD;           // [32768][4][32]
    short* m1bf  = pO    + (size_t)16 * NN * KSPLIT * HD; // [4096][1024]
    float* pl    = (float*)(m1bf + (size_t)ROWS * MLPD);  // [32768][4]
    float* a     = pl + (size_t)16 * NN * KSPLIT;         // [4096][256] f32

    // 0) weights -> bf16, MFMA-fragment-ordered
    transpose_frag<<<96, 256, 0, stream>>>(Wqkv, Wo, W1, W2, WqkvF, WoF, W1F, W2F);

    // 1) y = LN1(x)
    ln_kernel<<<ROWS / 4, 256, 0, stream>>>(x, ln1_g, ln1_b, ybf);

    // 2) qkv = y @ Wqkv + bqkv  (bf16 out)
    gemm_1w<256, false, false, true><<<dim3(12, 64), 64, 0, stream>>>(
        ybf, WqkvF, bqkv, nullptr, qkvbf, 3 * DIMD);

    // 3) V transpose
    transpose_v<<<dim3(NN / 64, BB * HH), 256, 0, stream>>>(qkvbf, vtg);

    // 4) attention partials + merge
    attn_mfma<<<dim3(NN / 64, BB * HH, KSPLIT), 256, 0, stream>>>(qkvbf, vtg, pO, pl);
    attn_merge<<<(16 * NN * HD) / 256, 256, 0, stream>>>(pO, pl, obf);

    // 5) a = o @ Wo + bo + x  (f32 out)
    gemm_1w<256, false, true, false><<<dim3(4, 64), 64, 0, stream>>>(
        obf, WoF, bo, x, a, DIMD);

    // 6) z = LN2(a)
    ln_kernel<<<ROWS / 4, 256, 0, stream>>>(a, ln2_g, ln2_b, zbf);

    // 7) m1 = gelu(z @ W1 + b1)  (bf16 out)
    gemm_1w<256, true, false, true><<<dim3(16, 64), 64, 0, stream>>>(
        zbf, W1F, b1, nullptr, m1bf, MLPD);

    // 8) out = m1 @ W2 + b2 + a  (f32 out)
    gemm_1w<1024, false, true, false><<<dim3(4, 64), 64, 0, stream>>>(
        m1bf, W2F, b2, a, out, DIMD);
}